// Round 14
// baseline (127.807 us; speedup 1.0000x reference)
//
#include <hip/hip_runtime.h>

#define K_CLUSTERS 512
#define D_FEAT 64
#define ROWS_PER_BLOCK 64
#define THREADS 256

typedef short bf16x8 __attribute__((ext_vector_type(8)));
typedef short bf16x4 __attribute__((ext_vector_type(4)));
typedef float f32x4 __attribute__((ext_vector_type(4)));

__device__ __forceinline__ unsigned short f32_to_bf16(float f) {
  unsigned int u = __float_as_uint(f);
  u += 0x7fffu + ((u >> 16) & 1u);   // RNE
  return (unsigned short)(u >> 16);
}
__device__ __forceinline__ unsigned short f32_to_bf16_trunc(float f) {
  return (unsigned short)(__float_as_uint(f) >> 16);
}
__device__ __forceinline__ float bf16_to_f32(unsigned short h) {
  return __uint_as_float(((unsigned int)h) << 16);
}
// raw 2^x — exact for |x| < ~126; our exponent is in [-50, 50]
__device__ __forceinline__ float vexp2(float a) {
  float r;
  asm("v_exp_f32 %0, %1" : "=v"(r) : "v"(a));
  return r;
}
// packed RNE f32x2 -> bf16x2 (low = a, high = b); no builtin on gfx950
__device__ __forceinline__ unsigned cvtpk_bf16(float a, float b) {
  unsigned r;
  asm("v_cvt_pk_bf16_f32 %0, %1, %2" : "=v"(r) : "v"(a), "v"(b));
  return r;
}

// W swizzle: element cx = c ^ ((row&7)<<3).
#define WSWZ(row) ((((unsigned)(row)) & 7u) << 3)

// ---------------- prep: one wave per cluster, lane = feature. Coalesced.
__global__ void kmeans_prep(const float* __restrict__ cent,
                            unsigned short* __restrict__ chi,   // [K][D]
                            unsigned short* __restrict__ clo,   // [K][D]
                            unsigned short* __restrict__ cthi,  // [D][K]
                            float* __restrict__ csqs) {         // [K], 10*log2e*|c|^2
  const int wv = threadIdx.x >> 6;
  const int lane = threadIdx.x & 63;
  const int k = blockIdx.x * 4 + wv;
  const int f = lane;
  float v = cent[k * D_FEAT + f];
  unsigned short h = f32_to_bf16_trunc(v);
  float rem = v - bf16_to_f32(h);
  unsigned short l = f32_to_bf16(rem);
  chi[k * D_FEAT + f] = h;
  clo[k * D_FEAT + f] = l;
  cthi[f * K_CLUSTERS + k] = f32_to_bf16(v);   // hi-only PV (R10)
  float s = v * v;
#pragma unroll
  for (int d = 1; d < 64; d <<= 1) s += __shfl_xor(s, d, 64);
  if (lane == 0) csqs[k] = s * 14.42695040888963f;  // 10 * log2(e)
}

// ---------------- main: R12 structure, K chunked 2x256 for 4 blocks/CU.
// R12 ledger: main 65us = 16 MFMA + 14 VALU + ~35 STALL, occupancy 2
// blocks/CU (LDS 64KB). The only unmeasured category is TLP at FULL
// per-wave ILP (R2/R4 halved chains; R3/R9 spilled). This round: W[64][256]
// = 32KB (staging aliased inside), LDS 32768 -> 4 blocks/CU at VGPR<=128
// ((256,2) cap, empirically 256/arg2). Per-STEP ILP byte-identical to R12;
// phases run twice (4 t-steps, 8 ks-steps each chunk), 5 barriers total.
// Watch FETCH for spill (oh/os now live across A(1): peak ~128 VGPR).
__global__ __launch_bounds__(THREADS, 2) void kmeans_main(
    const float* __restrict__ x,
    const unsigned short* __restrict__ chi,
    const unsigned short* __restrict__ clo,
    const unsigned short* __restrict__ cthi,
    const float* __restrict__ csqs,
    float* __restrict__ out) {
  // LDS: W [64][256] bf16 (32768 B, swizzled). x staging xh/xl [64][72]
  // (18432 B) aliases head of W (dead after frag loads, fenced by barrier).
  __shared__ __attribute__((aligned(16))) unsigned char smem[32768];
  unsigned short* xh = (unsigned short*)smem;            // [64][72]
  unsigned short* xl = xh + 64 * 72;                     // [64][72]
  unsigned short* W  = (unsigned short*)smem;            // [64][256] swizzled

  const int tid  = threadIdx.x;
  const int wv   = tid >> 6;
  const int lane = tid & 63;
  const int l16  = lane & 15;
  const int quad = lane >> 4;
  const long long rowbase = (long long)blockIdx.x * ROWS_PER_BLOCK;

  // ---- stage x -> xh/xl (float4 loads; hi=trunc pair-pack, lo=cvt_pk RNE) ----
  {
    int r  = tid >> 2;             // 0..63
    int f0 = (tid & 3) * 16;       // 0,16,32,48
    const float4* src4 = (const float4*)(x + (rowbase + r) * D_FEAT + f0);
#pragma unroll
    for (int i = 0; i < 4; ++i) {
      float4 v = src4[i];
      unsigned u0 = __float_as_uint(v.x), u1 = __float_as_uint(v.y);
      unsigned u2 = __float_as_uint(v.z), u3 = __float_as_uint(v.w);
      uint2 hp;
      hp.x = (u0 >> 16) | (u1 & 0xffff0000u);
      hp.y = (u2 >> 16) | (u3 & 0xffff0000u);
      float r0 = v.x - __uint_as_float(u0 & 0xffff0000u);
      float r1 = v.y - __uint_as_float(u1 & 0xffff0000u);
      float r2 = v.z - __uint_as_float(u2 & 0xffff0000u);
      float r3 = v.w - __uint_as_float(u3 & 0xffff0000u);
      uint2 lp;
      lp.x = cvtpk_bf16(r0, r1);
      lp.y = cvtpk_bf16(r2, r3);
      *(uint2*)(xh + r * 72 + f0 + i * 4) = hp;
      *(uint2*)(xl + r * 72 + f0 + i * 4) = lp;
    }
  }
  __syncthreads();   // B1: staging visible

  // ---- x fragments (persist across both chunks) ----
  bf16x8 ah[4][2], al[4][2];
#pragma unroll
  for (int rt = 0; rt < 4; ++rt)
#pragma unroll
    for (int ks = 0; ks < 2; ++ks) {
      ah[rt][ks] = *(const bf16x8*)(xh + (rt * 16 + l16) * 72 + ks * 32 + quad * 8);
      al[rt][ks] = *(const bf16x8*)(xl + (rt * 16 + l16) * 72 + ks * 32 + quad * 8);
    }
  __syncthreads();   // B2: xh/xl dead -> W region writable

  const int bko = quad * 8;
  const unsigned swz = ((unsigned)(l16 & 7)) << 3;   // row&7 == l16&7
  const int feat = wv * 16 + l16;
  const unsigned short* cth = cthi + feat * K_CLUSTERS;
  bf16x8 ones;
#pragma unroll
  for (int j = 0; j < 8; ++j) ones[j] = (short)0x3F80;

  f32x4 oh[4] = {{0.f,0.f,0.f,0.f},{0.f,0.f,0.f,0.f},{0.f,0.f,0.f,0.f},{0.f,0.f,0.f,0.f}};
  f32x4 os[4] = {{0.f,0.f,0.f,0.f},{0.f,0.f,0.f,0.f},{0.f,0.f,0.f,0.f},{0.f,0.f,0.f,0.f}};

#pragma unroll
  for (int ch = 0; ch < 2; ++ch) {
    // ---- Phase A(ch): wave's 64-cluster slice of this 256-chunk ----
    const int cbase = ch * 256 + wv * 64;
    bf16x8 pbh0[2], pbh1[2], pbl0[2], pbl1[2];
    f32x4 pcs4[2];
#pragma unroll
    for (int p = 0; p < 2; ++p) {
      int cl = cbase + p * 16 + l16;
      pbh0[p] = *(const bf16x8*)(chi + cl * 64 + bko);
      pbh1[p] = *(const bf16x8*)(chi + cl * 64 + 32 + bko);
      pbl0[p] = *(const bf16x8*)(clo + cl * 64 + bko);
      pbl1[p] = *(const bf16x8*)(clo + cl * 64 + 32 + bko);
      pcs4[p] = *(const f32x4*)(csqs + cbase + p * 16 + quad * 4);
    }
#pragma unroll
    for (int t = 0; t < 4; ++t) {
      const int sl = t & 1;
      bf16x8 cbh0 = pbh0[sl], cbh1 = pbh1[sl], cbl0 = pbl0[sl], cbl1 = pbl1[sl];
      f32x4 csq4 = pcs4[sl];
      if (t < 2) {   // prefetch t+2
        int cl = cbase + (t + 2) * 16 + l16;
        pbh0[sl] = *(const bf16x8*)(chi + cl * 64 + bko);
        pbh1[sl] = *(const bf16x8*)(chi + cl * 64 + 32 + bko);
        pbl0[sl] = *(const bf16x8*)(clo + cl * 64 + bko);
        pbl1[sl] = *(const bf16x8*)(clo + cl * 64 + 32 + bko);
        pcs4[sl] = *(const f32x4*)(csqs + cbase + (t + 2) * 16 + quad * 4);
      }
      const int c0l = wv * 64 + t * 16 + quad * 4;   // within-chunk column
      f32x4 av[4];
#pragma unroll
      for (int rt = 0; rt < 4; ++rt) {
        f32x4 a_hi = {0.f, 0.f, 0.f, 0.f};
        f32x4 a_lo = {0.f, 0.f, 0.f, 0.f};
        a_hi = __builtin_amdgcn_mfma_f32_16x16x32_bf16(cbh0, ah[rt][0], a_hi, 0, 0, 0);
        a_lo = __builtin_amdgcn_mfma_f32_16x16x32_bf16(cbh0, al[rt][0], a_lo, 0, 0, 0);
        a_hi = __builtin_amdgcn_mfma_f32_16x16x32_bf16(cbh1, ah[rt][1], a_hi, 0, 0, 0);
        a_lo = __builtin_amdgcn_mfma_f32_16x16x32_bf16(cbh1, al[rt][1], a_lo, 0, 0, 0);
        a_hi = __builtin_amdgcn_mfma_f32_16x16x32_bf16(cbl0, ah[rt][0], a_hi, 0, 0, 0);
        a_hi = __builtin_amdgcn_mfma_f32_16x16x32_bf16(cbl1, ah[rt][1], a_hi, 0, 0, 0);
        av[rt] = a_hi + a_lo;
      }
#pragma unroll
      for (int rt = 0; rt < 4; ++rt) {
        float e0 = vexp2(fmaf(28.85390081777927f, av[rt][0], -csq4[0]));
        float e1 = vexp2(fmaf(28.85390081777927f, av[rt][1], -csq4[1]));
        float e2 = vexp2(fmaf(28.85390081777927f, av[rt][2], -csq4[2]));
        float e3 = vexp2(fmaf(28.85390081777927f, av[rt][3], -csq4[3]));
        uint2 wp;
        wp.x = cvtpk_bf16(e0, e1);
        wp.y = cvtpk_bf16(e2, e3);
        *(uint2*)(W + (rt * 16 + l16) * 256 + ((unsigned)c0l ^ swz)) = wp;
      }
    }

    // ---- Phase C(ch) B prefetch issued before the barrier ----
    bf16x8 qbh[4];
#pragma unroll
    for (int p = 0; p < 4; ++p)
      qbh[p] = *(const bf16x8*)(cth + ch * 256 + p * 32 + quad * 8);

    __syncthreads();   // B3/B5: all waves' W writes visible

    // ---- Phase C(ch): wave's 16-feature slice, 256 clusters, hi-only PV ----
#pragma unroll
    for (int ksl = 0; ksl < 8; ++ksl) {
      const int sl = ksl & 3;
      bf16x8 bh = qbh[sl];
      if (ksl < 4)   // prefetch ksl+4
        qbh[sl] = *(const bf16x8*)(cth + ch * 256 + (ksl + 4) * 32 + quad * 8);
      const int ac = ksl * 32 + quad * 8;
      bf16x8 aw[4];
#pragma unroll
      for (int rt = 0; rt < 4; ++rt) {
        int arow = rt * 16 + l16;
        aw[rt] = *(const bf16x8*)(W + arow * 256 + ((unsigned)ac ^ WSWZ(arow)));
      }
#pragma unroll
      for (int rt = 0; rt < 4; ++rt) {
        oh[rt] = __builtin_amdgcn_mfma_f32_16x16x32_bf16(aw[rt], bh, oh[rt], 0, 0, 0);
        os[rt] = __builtin_amdgcn_mfma_f32_16x16x32_bf16(aw[rt], ones, os[rt], 0, 0, 0);
      }
    }
    if (ch == 0) __syncthreads();   // B4: C(0) reads done before A(1) rewrites W
  }

  // ---- epilogue: normalize by MFMA row sums (layout-aligned, no shuffles) ----
#pragma unroll
  for (int rt = 0; rt < 4; ++rt) {
    float* obase = out + (rowbase + rt * 16) * D_FEAT + feat;
#pragma unroll
    for (int r = 0; r < 4; ++r) {
      float val = oh[rt][r] * __builtin_amdgcn_rcpf(os[rt][r]);
      obase[(quad * 4 + r) * D_FEAT] = val;
    }
  }
}

extern "C" void kernel_launch(void* const* d_in, const int* in_sizes, int n_in,
                              void* d_out, int out_size, void* d_ws, size_t ws_size,
                              hipStream_t stream) {
  const float* x    = (const float*)d_in[0];
  const float* cent = (const float*)d_in[1];
  float* out        = (float*)d_out;

  unsigned short* chi  = (unsigned short*)d_ws;
  unsigned short* clo  = chi  + K_CLUSTERS * D_FEAT;
  unsigned short* cthi = clo  + K_CLUSTERS * D_FEAT;
  float*          csqs = (float*)(cthi + K_CLUSTERS * D_FEAT);

  kmeans_prep<<<K_CLUSTERS / 4, 256, 0, stream>>>(
      cent, chi, clo, cthi, csqs);

  int nrows = in_sizes[0] / D_FEAT;  // 131072
  kmeans_main<<<nrows / ROWS_PER_BLOCK, THREADS, 0, stream>>>(
      x, chi, clo, cthi, csqs, out);
}